// Round 6
// baseline (505.643 us; speedup 1.0000x reference)
//
#include <hip/hip_runtime.h>
#include <stdint.h>

typedef unsigned short u16;
typedef short short8 __attribute__((ext_vector_type(8)));
typedef float f32x4 __attribute__((ext_vector_type(4)));

// Problem sizes: B=16384, D=768, E=124 (pad 128), C=6, E*C=744 (pad 768)
#define NB 16384

// ---- workspace layout (bytes) ----
#define OFF_XHI      0ull            // bf16 [16384][768]
#define OFF_XLO      25165824ull     // bf16 [16384][768]
#define OFF_LCLS     0ull            // aliases XHI: bf16 [16384][768] class logits (cols 0..743 real)
#define OFF_BT1      50331648ull     // bf16 [1536][768]  (cls_w1^T ; ew_w1^T)  [dead after gemm1]
#define OFF_LEWB     50331648ull     // bf16 [16384][128] ew logits (aliases BT1 region, written in gemm2)
#define OFF_BTWE_HI  52690944ull     // bf16 [768][768]
#define OFF_BTWE_LO  53870592ull
#define OFF_BT2CLS   55050240ull     // bf16 [768][768] (744 real rows, padded w/ 0)
#define OFF_BT2EW    56229888ull     // bf16 [128][768]
#define OFF_BT2WE_HI 56426496ull
#define OFF_BT2WE_LO 56623104ull
#define OFF_B1CE     56819712ull     // f32 [1536]
#define OFF_B1WE     56825856ull     // f32 [768]
#define OFF_B2CLS    56828928ull     // f32 [768]
#define OFF_B2EW     56832000ull     // f32 [128]
#define OFF_B2WE     56832512ull     // f32 [128]
#define OFF_HCLSEW   56833024ull     // bf16 [16384][1536] gelu(h) for cls|ew
#define OFF_PWE      107164672ull    // f32 [16384][128] we logits (full K reduction, single buffer)
#define WS_NEED      157496320ull

__device__ __forceinline__ u16 f2bf(float f) {          // RNE f32->bf16
  uint32_t u = __float_as_uint(f);
  u += 0x7fffu + ((u >> 16) & 1u);
  return (u16)(u >> 16);
}
__device__ __forceinline__ float bf2f(u16 h) {
  return __uint_as_float(((uint32_t)h) << 16);
}
__device__ __forceinline__ uint32_t pk2(float a, float b) {   // pack 2 bf16 into u32
  return (uint32_t)f2bf(a) | ((uint32_t)f2bf(b) << 16);
}
__device__ __forceinline__ void g2l16(const u16* g, u16* l) {
  // async global->LDS, 16B/lane; LDS dest = wave-uniform base + lane*16 (HW rule).
  // Global side is a normal per-lane address -> per-lane source permutation is legal.
  __builtin_amdgcn_global_load_lds(
      (__attribute__((address_space(1))) void*)(u16*)g,
      (__attribute__((address_space(3))) void*)l, 16, 0, 0);
}

// branch-free exact-GELU: 0.5*v*(1+erf(v/sqrt2)), erf via A&S 7.1.26 (|eps|<=1.5e-7).
__device__ __forceinline__ float gelu_exact(float v) {
  const float x = fabsf(v) * 0.70710678118654752f;
  const float t = __fdividef(1.0f, __builtin_fmaf(0.3275911f, x, 1.0f));
  float p = __builtin_fmaf(1.061405429f, t, -1.453152027f);
  p = __builtin_fmaf(p, t, 1.421413741f);
  p = __builtin_fmaf(p, t, -0.284496736f);
  p = __builtin_fmaf(p, t, 0.254829592f);
  p = p * t;
  const float e = __expf(-x * x);
  float erfx = __builtin_fmaf(-p, e, 1.0f);
  erfx = (v < 0.f) ? -erfx : erfx;
  return 0.5f * v * (1.0f + erfx);
}

// ---------------- merged prep: cvt_x split + weight transposes + bias concat ----------------
// grid layout: [0,12288) cvt_x ; [12288,13152) transpose (12x12x6) ; [13152,13165) bias
__global__ void prep_all(
    const float* __restrict__ x, u16* __restrict__ xhi, u16* __restrict__ xlo,
    const float* __restrict__ cls_w1, const float* __restrict__ ew_w1,
    const float* __restrict__ we_w1,  const float* __restrict__ cls_w2,
    const float* __restrict__ ew_w2,  const float* __restrict__ we_w2,
    u16* BT1, u16* BTwe_hi, u16* BTwe_lo,
    u16* BT2cls, u16* BT2ew, u16* BT2we_hi, u16* BT2we_lo,
    const float* __restrict__ cls_b1, const float* __restrict__ ew_b1,
    const float* __restrict__ we_b1,  const float* __restrict__ cls_b2,
    const float* __restrict__ ew_b2,  const float* __restrict__ we_b2,
    float* b1ce, float* b1we, float* b2cls, float* b2ew, float* b2we) {
  __shared__ float t[64][65];
  const int bid = blockIdx.x;
  if (bid < 12288) {                       // ---- x -> (hi,lo) bf16 split
    int i = bid * 256 + threadIdx.x;       // 12288*256 = 16384*768/4 exact
    float4 v = ((const float4*)x)[i];
    ushort4 h, l;
    h.x = f2bf(v.x); l.x = f2bf(v.x - bf2f(h.x));
    h.y = f2bf(v.y); l.y = f2bf(v.y - bf2f(h.y));
    h.z = f2bf(v.z); l.z = f2bf(v.z - bf2f(h.z));
    h.w = f2bf(v.w); l.w = f2bf(v.w - bf2f(h.w));
    ((ushort4*)xhi)[i] = h;
    ((ushort4*)xlo)[i] = l;
    return;
  }
  if (bid < 13152) {                       // ---- LDS-tiled transpose W[768][N] -> BT[Npad][768]
    const int idx = bid - 12288;
    const int bx = idx % 12, by = (idx / 12) % 12, bz = idx / 144;
    const float* src; int N; u16* dhi; u16* dlo = nullptr;
    switch (bz) {
      case 0: src = cls_w1; N = 768; dhi = BT1; break;
      case 1: src = ew_w1;  N = 768; dhi = BT1 + 768 * 768; break;
      case 2: src = we_w1;  N = 768; dhi = BTwe_hi; dlo = BTwe_lo; break;
      case 3: src = cls_w2; N = 744; dhi = BT2cls; break;
      case 4: src = ew_w2;  N = 124; dhi = BT2ew; break;
      default: src = we_w2; N = 124; dhi = BT2we_hi; dlo = BT2we_lo; break;
    }
    const int Npad = (N + 127) & ~127;
    const int n0 = by * 64;
    if (n0 >= Npad) return;
    const int k0 = bx * 64;
    const int tx = threadIdx.x & 63, tg = threadIdx.x >> 6;
#pragma unroll
    for (int r = 0; r < 16; ++r) {
      int k = tg * 16 + r;
      int n = n0 + tx;
      t[k][tx] = (n < N) ? src[(size_t)(k0 + k) * N + n] : 0.f;   // coalesced read
    }
    __syncthreads();
#pragma unroll
    for (int r = 0; r < 16; ++r) {
      int n = n0 + tg * 16 + r;
      if (n < Npad) {
        float v = t[tx][tg * 16 + r];
        u16 h = f2bf(v);
        dhi[(size_t)n * 768 + k0 + tx] = h;                       // coalesced write
        if (dlo) dlo[(size_t)n * 768 + k0 + tx] = f2bf(v - bf2f(h));
      }
    }
    return;
  }
  // ---- bias concat/pad: 13 blocks * 256 = 3328 = 1536+768+768+128+128 exact
  int id = (bid - 13152) * 256 + threadIdx.x;
  if (id < 1536) { b1ce[id] = (id < 768) ? cls_b1[id] : ew_b1[id - 768]; return; }
  id -= 1536;
  if (id < 768) { b1we[id] = we_b1[id]; return; }
  id -= 768;
  if (id < 768) { b2cls[id] = (id < 744) ? cls_b2[id] : 0.f; return; }
  id -= 768;
  if (id < 128) { b2ew[id] = (id < 124) ? ew_b2[id] : 0.f; return; }
  id -= 128;
  if (id < 128) { b2we[id] = (id < 124) ? we_b2[id] : 0.f; return; }
}

// ---------------- GEMM core: 128x128 tile, BK=64, 4 waves 2x2, XOR-swizzled LDS ----------------
// LDS: logical (row, c8) at physical c8p = c8 ^ (row&7) -> conflict-free ds_read_b128 (0 conflicts).
// MFMA operands SWAPPED (bv, av) -> acc holds C^T fragments: lane owns ONE row (lane&15 within
// frag) and 4 CONSECUTIVE cols ((lane>>4)*4 + r). Enables packed dwordx2/dwordx4 epilogue stores.
__device__ __forceinline__ void gemm_core(
    const u16* A0, int lda,
    const u16* B0,                                  // pre-offset by bn*K
    int K, int bm, int tid, u16* sA, u16* sB, f32x4 acc[4][4]) {
  const int lane = tid & 63;
  const int wv = tid >> 6;
  const int wr = wv >> 1, wc = wv & 1;
  const int sr = lane >> 3;                        // staging row within 8-row group
  const int sc = (((lane & 7) ^ sr) << 3);         // swizzled source col group
  const u16* gA = A0 + (size_t)(bm + wv * 32 + sr) * lda + sc;
  const u16* gB = B0 + (size_t)(wv * 32 + sr) * K + sc;
  u16* lA = sA + (wv * 32) * 64;
  u16* lB = sB + (wv * 32) * 64;
  for (int kt = 0; kt < K; kt += 64) {
#pragma unroll
    for (int s = 0; s < 4; ++s) {
      g2l16(gA + (size_t)(s * 8) * lda + kt, lA + s * 8 * 64);
      g2l16(gB + (size_t)(s * 8) * K + kt, lB + s * 8 * 64);
    }
    __syncthreads();
#pragma unroll
    for (int ks = 0; ks < 2; ++ks) {
      const int co = ((ks * 4 + (lane >> 4)) ^ (lane & 7)) * 8;  // row&7 == lane&7 for all frags
      short8 av[4], bv[4];
#pragma unroll
      for (int i = 0; i < 4; i++)
        av[i] = *(const short8*)(sA + (wr * 64 + i * 16 + (lane & 15)) * 64 + co);
#pragma unroll
      for (int j = 0; j < 4; j++)
        bv[j] = *(const short8*)(sB + (wc * 64 + j * 16 + (lane & 15)) * 64 + co);
#pragma unroll
      for (int i = 0; i < 4; i++)
#pragma unroll
        for (int j = 0; j < 4; j++)
          acc[i][j] = __builtin_amdgcn_mfma_f32_16x16x32_bf16(bv[j], av[i], acc[i][j], 0, 0, 0);
    }
    __syncthreads();
  }
}

// ---------------- packed hi/lo split core: C = Ahi*Bhi^T + Alo*Bhi^T + Ahi*Blo^T, ONE K-loop ----------------
// LDS rows pack [hi(32)|lo(32)] = 128B/row -> proven XOR-8 granule swizzle unchanged; hi/lo select
// is per-lane on the global_load_lds source address. 48 MFMA per wave per barrier-pair.
// MFMA operands swapped (C^T fragments) like gemm_core.
__device__ __forceinline__ void gemm_split_core(
    const u16* __restrict__ Ahi, const u16* __restrict__ Alo, int lda,
    const u16* __restrict__ Bhi, const u16* __restrict__ Blo, int ldb,  // pre-offset to tile row 0
    int K, int bm, int tid, u16* sA, u16* sB, f32x4 acc[4][4]) {
  const int lane = tid & 63;
  const int wv = tid >> 6;
  const int wr = wv >> 1, wc = wv & 1;
  const int sr = lane >> 3;                  // row within 8-row staging group
  const int gl = (lane & 7) ^ sr;            // logical granule at this lane's phys slot
  const int koff = (gl & 3) << 3;            // element offset within the 32-elem half
  const u16* Asel = (gl < 4) ? Ahi : Alo;
  const u16* Bsel = (gl < 4) ? Bhi : Blo;
  const u16* gA = Asel + (size_t)(bm + wv * 32 + sr) * lda + koff;
  const u16* gB = Bsel + (size_t)(wv * 32 + sr) * ldb + koff;
  u16* lA = sA + (wv * 32) * 64;
  u16* lB = sB + (wv * 32) * 64;

  for (int kt = 0; kt < K; kt += 32) {
#pragma unroll
    for (int s = 0; s < 4; ++s) {
      g2l16(gA + (size_t)(s * 8) * lda + kt, lA + s * 8 * 64);
      g2l16(gB + (size_t)(s * 8) * ldb + kt, lB + s * 8 * 64);
    }
    __syncthreads();
    // fragment granule: hi at (kg ^ row&7), lo at same ^ 4 -> element offset ^32
    const int coh = (((lane >> 4) ^ (lane & 7)) << 3);
    short8 ah[4], al[4], bh[4], bl[4];
#pragma unroll
    for (int i = 0; i < 4; i++) {
      const u16* p = sA + (wr * 64 + i * 16 + (lane & 15)) * 64;
      ah[i] = *(const short8*)(p + coh);
      al[i] = *(const short8*)(p + (coh ^ 32));
    }
#pragma unroll
    for (int j = 0; j < 4; j++) {
      const u16* p = sB + (wc * 64 + j * 16 + (lane & 15)) * 64;
      bh[j] = *(const short8*)(p + coh);
      bl[j] = *(const short8*)(p + (coh ^ 32));
    }
#pragma unroll
    for (int i = 0; i < 4; i++)
#pragma unroll
      for (int j = 0; j < 4; j++) {
        acc[i][j] = __builtin_amdgcn_mfma_f32_16x16x32_bf16(bh[j], ah[i], acc[i][j], 0, 0, 0);
        acc[i][j] = __builtin_amdgcn_mfma_f32_16x16x32_bf16(bh[j], al[i], acc[i][j], 0, 0, 0);
        acc[i][j] = __builtin_amdgcn_mfma_f32_16x16x32_bf16(bl[j], ah[i], acc[i][j], 0, 0, 0);
      }
    __syncthreads();
  }
}

// XCD/L2 swizzle for 128-row tiles: xcd=bid&7 owns 16 row-chunks; 8-row sub-bands, rows fastest.
__device__ __forceinline__ void decode_bid(int bid, int NC, int& bm, int& bn) {
  const int xcd = bid & 7, slot = bid >> 3;
  const int per = NC << 3;
  const int sub = slot / per, rem = slot - sub * per;
  const int colu = rem >> 3, rowIn = rem & 7;
  bm = ((xcd << 4) + (sub << 3) + rowIn) << 7;
  bn = colu << 7;
}

// ---------------- fused fc1 + FULL we-fc2 fold: BOTH heads in one dispatch ----------------
// bid [0,128)    -> which_expert COMPLETE pipeline for 128 rows: loop over all 6 hidden
//                   col-tiles {fc1 packed-split GEMM -> bias+gelu -> hi/lo LDS tile ->
//                   fold-GEMM vs w2 hi/lo accumulating acc2}. ONE f32 [16384][128] output
//                   (8.4 MB), bias added once. h_we never goes to global; no partial slices.
// bid [128,1664) -> cls+ew fc1 GEMM (light, backfills; we stragglers hidden under these)
__global__ __launch_bounds__(256, 3) void gemm1_fused(
    const u16* __restrict__ Ahi, const u16* __restrict__ Alo,      // xhi, xlo [16384][768]
    const u16* __restrict__ Bwe_hi, const u16* __restrict__ Bwe_lo,// we_w1^T splits [768][768]
    const u16* __restrict__ BT1,                                   // [cls_w1^T; ew_w1^T] [1536][768]
    const float* __restrict__ b1we, const float* __restrict__ b1ce,
    const u16* __restrict__ BT2we_hi, const u16* __restrict__ BT2we_lo, // we_w2^T splits [128][768]
    const float* __restrict__ b2we,
    float* __restrict__ pwe,                                       // f32 [16384][128] we logits
    u16* __restrict__ out_ce) {                                    // [16384][1536]
  __shared__ u16 smem[2 * 128 * 64];
  u16* sA = smem;
  u16* sB = smem + 128 * 64;
  const int tid = threadIdx.x;
  const int lane = tid & 63;
  const int wv = tid >> 6;
  const int wr = wv >> 1, wc = wv & 1;
  const int K = 768;

  f32x4 acc[4][4];
#pragma unroll
  for (int i = 0; i < 4; i++)
#pragma unroll
    for (int j = 0; j < 4; j++) acc[i][j] = f32x4{0.f, 0.f, 0.f, 0.f};

  if (blockIdx.x < 128) {
    // ===== which_expert: full fc1+fc2 for 128 rows =====
    const int r = blockIdx.x;
    const int bm = (((r & 7) << 4) + (r >> 3)) << 7;   // XCD-banded row chunk

    const int lg4 = (lane >> 4) << 2;
    const int sr = lane >> 3;
    const int gl = (lane & 7) ^ sr;
    const int koff = (gl & 3) << 3;
    const u16* Bsel2 = (gl < 4) ? BT2we_hi : BT2we_lo;
    u16* lB = sB + (wv * 32) * 64;
    const int coh = (((lane >> 4) ^ (lane & 7)) << 3);

    f32x4 acc2[4][4];
#pragma unroll
    for (int i = 0; i < 4; i++)
#pragma unroll
      for (int j = 0; j < 4; j++) acc2[i][j] = f32x4{0.f, 0.f, 0.f, 0.f};

#pragma unroll 1
    for (int t = 0; t < 6; ++t) {
      const int bn = t << 7;
      // ---- fc1 for hidden cols [bn, bn+128)
#pragma unroll
      for (int i = 0; i < 4; i++)
#pragma unroll
        for (int j = 0; j < 4; j++) acc[i][j] = f32x4{0.f, 0.f, 0.f, 0.f};
      gemm_split_core(Ahi, Alo, K, Bwe_hi + (size_t)bn * K, Bwe_lo + (size_t)bn * K, K,
                      K, bm, tid, sA, sB, acc);

      // ---- fold: 4 chunks of 32 hidden-k; A = gelu(h) hi/lo in sA; B = w2 hi/lo in sB
      const u16* gB2 = Bsel2 + (size_t)(wv * 32 + sr) * 768 + bn + koff;
#pragma unroll
      for (int c = 0; c < 4; ++c) {
        // stage w2 chunk: expert rows 0..127 x 32 k (hi|lo packed), split-core layout
#pragma unroll
        for (int s = 0; s < 4; ++s)
          g2l16(gB2 + (size_t)(s * 8) * 768 + (c << 5), lB + s * 8 * 64);
        // waves owning this chunk's h cols write gelu(h) hi/lo into sA
        if (wc == (c >> 1)) {
#pragma unroll
          for (int i = 0; i < 4; i++) {
            const int row = wr * 64 + i * 16 + (lane & 15);     // tile-local m row
            const int rs = row & 7;
            u16* lrow = sA + row * 64;
#pragma unroll
            for (int jj = 0; jj < 2; jj++) {
              const int j = ((c & 1) << 1) + jj;
              const int col = bn + wc * 64 + j * 16 + lg4;       // global hidden col
              const float4 bs = *(const float4*)(b1we + col);
              float g0 = gelu_exact(acc[i][j][0] + bs.x);
              float g1 = gelu_exact(acc[i][j][1] + bs.y);
              float g2 = gelu_exact(acc[i][j][2] + bs.z);
              float g3 = gelu_exact(acc[i][j][3] + bs.w);
              u16 h0 = f2bf(g0), h1 = f2bf(g1), h2 = f2bf(g2), h3 = f2bf(g3);
              uint2 hv, lv;
              hv.x = (uint32_t)h0 | ((uint32_t)h1 << 16);
              hv.y = (uint32_t)h2 | ((uint32_t)h3 << 16);
              lv.x = pk2(g0 - bf2f(h0), g1 - bf2f(h1));
              lv.y = pk2(g2 - bf2f(h2), g3 - bf2f(h3));
              const int kk = ((j & 1) << 4) + lg4;               // k-elem within chunk
              const int gr = kk >> 3;                            // logical granule 0..3
              const int off = kk & 7;                            // 0 or 4
              *(uint2*)(lrow + ((gr ^ rs) << 3) + off) = hv;         // hi granule
              *(uint2*)(lrow + (((gr ^ rs) ^ 4) << 3) + off) = lv;   // lo granule (^4)
            }
          }
        }
        __syncthreads();
        short8 ah[4], al[4], bh[4], bl[4];
#pragma unroll
        for (int i = 0; i < 4; i++) {
          const u16* p = sA + (wr * 64 + i * 16 + (lane & 15)) * 64;
          ah[i] = *(const short8*)(p + coh);
          al[i] = *(const short8*)(p + (coh ^ 32));
        }
#pragma unroll
        for (int j = 0; j < 4; j++) {
          const u16* p = sB + (wc * 64 + j * 16 + (lane & 15)) * 64;
          bh[j] = *(const short8*)(p + coh);
          bl[j] = *(const short8*)(p + (coh ^ 32));
        }
#pragma unroll
        for (int i = 0; i < 4; i++)
#pragma unroll
          for (int j = 0; j < 4; j++) {
            acc2[i][j] = __builtin_amdgcn_mfma_f32_16x16x32_bf16(bh[j], ah[i], acc2[i][j], 0, 0, 0);
            acc2[i][j] = __builtin_amdgcn_mfma_f32_16x16x32_bf16(bh[j], al[i], acc2[i][j], 0, 0, 0);
            acc2[i][j] = __builtin_amdgcn_mfma_f32_16x16x32_bf16(bl[j], ah[i], acc2[i][j], 0, 0, 0);
          }
        __syncthreads();
      }
    }
    // ---- store full we logits (f32) + bias, single buffer
#pragma unroll
    for (int i = 0; i < 4; i++) {
      const int row = bm + wr * 64 + i * 16 + (lane & 15);
#pragma unroll
      for (int j = 0; j < 4; j++) {
        const int e0 = wc * 64 + j * 16 + lg4;
        const float4 bs = *(const float4*)(b2we + e0);
        float4 v = make_float4(acc2[i][j][0] + bs.x, acc2[i][j][1] + bs.y,
                               acc2[i][j][2] + bs.z, acc2[i][j][3] + bs.w);
        *(float4*)(pwe + (size_t)row * 128 + e0) = v;
      }
    }
  } else {
    // ===== cls+ew fc1 (N=1536), gelu -> bf16, packed dwordx2 stores =====
    int bm, bn;
    decode_bid(blockIdx.x - 128, 12, bm, bn);
    gemm_core(Ahi, 768, BT1 + (size_t)bn * K, K, bm, tid, sA, sB, acc);
    const int lg4 = (lane >> 4) << 2;
#pragma unroll
    for (int i = 0; i < 4; i++) {
      const int row = bm + wr * 64 + i * 16 + (lane & 15);
      u16* ro = out_ce + (size_t)row * 1536;
#pragma unroll
      for (int j = 0; j < 4; j++) {
        const int colb = bn + wc * 64 + j * 16 + lg4;
        const float4 bs = *(const float4*)(b1ce + colb);
        uint2 hv;
        hv.x = pk2(gelu_exact(acc[i][j][0] + bs.x), gelu_exact(acc[i][j][1] + bs.y));
        hv.y = pk2(gelu_exact(acc[i][j][2] + bs.z), gelu_exact(acc[i][j][3] + bs.w));
        *(uint2*)(ro + colb) = hv;
      }
    }
  }
}

// fused fc2 (we path folded into gemm1):
//   bid [0,768)   -> cls (1u, 12 K-tiles)
//   bid [768,896) -> ew  (1u) -> bf16 Lew   (last: backfills the drain)
//   896 blocks <= 1024 -> single residency round.
__global__ __launch_bounds__(256, 4) void gemm2_fused(
    const u16* __restrict__ h_cls,                  // [16384][1536]: cls cols 0..767, ew cols 768..1535
    const u16* __restrict__ BT2cls, const u16* __restrict__ BT2ew,
    const float* __restrict__ b2cls, const float* __restrict__ b2ew,
    u16* __restrict__ Lcls, u16* __restrict__ LewB) {
  __shared__ u16 sA[128 * 64];
  __shared__ u16 sB[128 * 64];
  const int tid = threadIdx.x;
  const int lane = tid & 63;
  const int wr = (tid >> 6) >> 1, wc = (tid >> 6) & 1;
  const int lg4 = (lane >> 4) << 2;

  f32x4 acc[4][4];
#pragma unroll
  for (int i = 0; i < 4; i++)
#pragma unroll
    for (int j = 0; j < 4; j++) acc[i][j] = f32x4{0.f, 0.f, 0.f, 0.f};

  const int bid = blockIdx.x;
  if (bid < 768) {                         // ---- cls: 6 col-tiles, packed dwordx2 stores
    int bm, bn;
    decode_bid(bid, 6, bm, bn);
    gemm_core(h_cls, 1536, BT2cls + (size_t)bn * 768, 768, bm, tid, sA, sB, acc);
#pragma unroll
    for (int i = 0; i < 4; i++) {
      const int row = bm + wr * 64 + i * 16 + (lane & 15);
      u16* ro = Lcls + (size_t)row * 768;
#pragma unroll
      for (int j = 0; j < 4; j++) {
        const int colb = bn + wc * 64 + j * 16 + lg4;
        const float4 bs = *(const float4*)(b2cls + colb);
        uint2 hv;
        hv.x = pk2(acc[i][j][0] + bs.x, acc[i][j][1] + bs.y);
        hv.y = pk2(acc[i][j][2] + bs.z, acc[i][j][3] + bs.w);
        *(uint2*)(ro + colb) = hv;
      }
    }
  } else {                                 // ---- ew (K=768 from h cols 768..1535) -> bf16
    const int r = bid - 768;
    const int bm = (((r & 7) << 4) + (r >> 3)) << 7;
    gemm_core(h_cls + 768, 1536, BT2ew, 768, bm, tid, sA, sB, acc);
#pragma unroll
    for (int i = 0; i < 4; i++) {
      const int row = bm + wr * 64 + i * 16 + (lane & 15);
      u16* ro = LewB + (size_t)row * 128;
#pragma unroll
      for (int j = 0; j < 4; j++) {
        const int colb = wc * 64 + j * 16 + lg4;
        const float4 bs = *(const float4*)(b2ew + colb);
        uint2 hv;
        hv.x = pk2(acc[i][j][0] + bs.x, acc[i][j][1] + bs.y);
        hv.y = pk2(acc[i][j][2] + bs.z, acc[i][j][3] + bs.w);
        *(uint2*)(ro + colb) = hv;
      }
    }
  }
}

// ---------------- finalize: rank-select mask (== reference threshold), softmaxes, mixture ----------------
// which_expert = pwe (single f32 buffer, full K reduction done in gemm1).
// keep_i  <=>  which_i >= n-th largest  <=>  #{j : w_j > w_i} < n   (ties keep both, same as ref)
__global__ __launch_bounds__(256) void finalize(
    const u16* __restrict__ Lcls,   // bf16 [B][768], expert e at cols e*6..e*6+5
    const float* __restrict__ pwe,  // f32 [16384][128]
    const u16* __restrict__ LewB,   // bf16 [B][128]
    const int* __restrict__ nexp, float* __restrict__ out) {
  const int bid = blockIdx.x;
  const int g = ((bid & 7) << 9) + (bid >> 3);      // XCD band
  const int b = (g << 2) + (int)(threadIdx.x >> 6); // 4 rows/block, one wave each
  const int lane = threadIdx.x & 63;
  const float NEG = -3.0e38f;
  const size_t base = (size_t)b * 128;
  const float w0 = (lane < 124) ? pwe[base + lane] : NEG;
  const float w1 = (lane < 60) ? pwe[base + 64 + lane] : NEG;
  int r0 = 0, r1 = 0;
#pragma unroll
  for (int j = 0; j < 64; ++j) {
    float v = __shfl(w0, j, 64);
    r0 += (v > w0); r1 += (v > w1);
  }
#pragma unroll
  for (int j = 0; j < 64; ++j) {
    float v = __shfl(w1, j, 64);
    r0 += (v > w0); r1 += (v > w1);
  }
  int n = nexp[b];
  n = n < 1 ? 1 : (n > 124 ? 124 : n);
  const bool k0 = (lane < 124) && (r0 < n);
  const bool k1 = (lane < 60) && (r1 < n);
  float l0 = k0 ? bf2f(LewB[base + lane]) : NEG;
  float l1 = k1 ? bf2f(LewB[base + 64 + lane]) : NEG;
  float mx = fmaxf(l0, l1);
#pragma unroll
  for (int o = 32; o > 0; o >>= 1) mx = fmaxf(mx, __shfl_xor(mx, o, 64));
  float e0 = k0 ? __expf(l0 - mx) : 0.f;
  float e1 = k1 ? __expf(l1 - mx) : 0.f;
  float S = e0 + e1;
#pragma unroll
  for (int o = 32; o > 0; o >>= 1) S += __shfl_xor(S, o, 64);
  float a0 = 0, a1 = 0, a2 = 0, a3 = 0, a4 = 0, a5 = 0;
#pragma unroll
  for (int h = 0; h < 2; ++h) {
    int e = lane + h * 64;
    float we = h ? e1 : e0;
    if (we > 0.f) {
      const u16* lp = Lcls + (size_t)b * 768 + e * 6;
      float c0 = bf2f(lp[0]), c1 = bf2f(lp[1]), c2 = bf2f(lp[2]);
      float c3 = bf2f(lp[3]), c4 = bf2f(lp[4]), c5 = bf2f(lp[5]);
      float m = fmaxf(fmaxf(fmaxf(c0, c1), fmaxf(c2, c3)), fmaxf(c4, c5));
      float q0 = __expf(c0 - m), q1 = __expf(c1 - m), q2 = __expf(c2 - m);
      float q3 = __expf(c3 - m), q4 = __expf(c4 - m), q5 = __expf(c5 - m);
      float inv = we / (q0 + q1 + q2 + q3 + q4 + q5);
      a0 += q0 * inv; a1 += q1 * inv; a2 += q2 * inv;
      a3 += q3 * inv; a4 += q4 * inv; a5 += q5 * inv;
    }
  }
#pragma unroll
  for (int o = 32; o > 0; o >>= 1) {
    a0 += __shfl_xor(a0, o, 64); a1 += __shfl_xor(a1, o, 64);
    a2 += __shfl_xor(a2, o, 64); a3 += __shfl_xor(a3, o, 64);
    a4 += __shfl_xor(a4, o, 64); a5 += __shfl_xor(a5, o, 64);
  }
  if (lane < 6) {
    float v = (lane == 0) ? a0 : (lane == 1) ? a1 : (lane == 2) ? a2
              : (lane == 3) ? a3 : (lane == 4) ? a4 : a5;
    out[(size_t)b * 6 + lane] = v / S;
  }
}

__global__ void fill_sentinel(float* out, int n, float v) {
  int i = blockIdx.x * 256 + threadIdx.x;
  if (i < n) out[i] = v;
}

extern "C" void kernel_launch(void* const* d_in, const int* in_sizes, int n_in,
                              void* d_out, int out_size, void* d_ws, size_t ws_size,
                              hipStream_t stream) {
  const float* x = (const float*)d_in[0];
  const int* nexp = (const int*)d_in[1];
  const float* cls_w1 = (const float*)d_in[2];
  const float* cls_b1 = (const float*)d_in[3];
  const float* cls_w2 = (const float*)d_in[4];
  const float* cls_b2 = (const float*)d_in[5];
  const float* we_w1 = (const float*)d_in[6];
  const float* we_b1 = (const float*)d_in[7];
  const float* we_w2 = (const float*)d_in[8];
  const float* we_b2 = (const float*)d_in[9];
  const float* ew_w1 = (const float*)d_in[10];
  const float* ew_b1 = (const float*)d_in[11];
  const float* ew_w2 = (const float*)d_in[12];
  const float* ew_b2 = (const float*)d_in[13];
  float* out = (float*)d_out;
  char* ws = (char*)d_ws;

  if (ws_size < WS_NEED) {  // diagnosable failure: absmax ~12345
    fill_sentinel<<<(out_size + 255) / 256, 256, 0, stream>>>(out, out_size, 12345.0f);
    return;
  }

  u16* xhi = (u16*)(ws + OFF_XHI);
  u16* xlo = (u16*)(ws + OFF_XLO);
  u16* Lcls = (u16*)(ws + OFF_LCLS);
  u16* LewB = (u16*)(ws + OFF_LEWB);
  u16* BT1 = (u16*)(ws + OFF_BT1);
  u16* BTwe_hi = (u16*)(ws + OFF_BTWE_HI);
  u16* BTwe_lo = (u16*)(ws + OFF_BTWE_LO);
  u16* BT2cls = (u16*)(ws + OFF_BT2CLS);
  u16* BT2ew = (u16*)(ws + OFF_BT2EW);
  u16* BT2we_hi = (u16*)(ws + OFF_BT2WE_HI);
  u16* BT2we_lo = (u16*)(ws + OFF_BT2WE_LO);
  float* b1ce = (float*)(ws + OFF_B1CE);
  float* b1we = (float*)(ws + OFF_B1WE);
  float* b2cls = (float*)(ws + OFF_B2CLS);
  float* b2ew = (float*)(ws + OFF_B2EW);
  float* b2we = (float*)(ws + OFF_B2WE);
  u16* h_clsew = (u16*)(ws + OFF_HCLSEW);
  float* pwe = (float*)(ws + OFF_PWE);

  prep_all<<<13165, 256, 0, stream>>>(x, xhi, xlo,
                                      cls_w1, ew_w1, we_w1, cls_w2, ew_w2, we_w2,
                                      BT1, BTwe_hi, BTwe_lo, BT2cls, BT2ew, BT2we_hi, BT2we_lo,
                                      cls_b1, ew_b1, we_b1, cls_b2, ew_b2, we_b2,
                                      b1ce, b1we, b2cls, b2ew, b2we);
  // fc1 BOTH heads + full we-fc2 fold: 128 heavy we blocks first, 1536 cls/ew backfill
  gemm1_fused<<<1664, 256, 0, stream>>>(xhi, xlo, BTwe_hi, BTwe_lo, BT1,
                                        b1we, b1ce, BT2we_hi, BT2we_lo, b2we,
                                        pwe, h_clsew);
  // fc2: 896 blocks (cls + ew only), single residency round
  gemm2_fused<<<896, 256, 0, stream>>>(h_clsew, BT2cls, BT2ew,
                                       b2cls, b2ew, Lcls, LewB);
  finalize<<<4096, 256, 0, stream>>>(Lcls, pwe, LewB, nexp, out);
}

// Round 7
// 333.503 us; speedup vs baseline: 1.5162x; 1.5162x over previous
//
#include <hip/hip_runtime.h>
#include <stdint.h>

typedef unsigned short u16;
typedef short short8 __attribute__((ext_vector_type(8)));
typedef float f32x4 __attribute__((ext_vector_type(4)));

// Problem sizes: B=16384, D=768, E=124 (pad 128), C=6, E*C=744 (pad 768)
#define NB 16384

// ---- workspace layout (bytes) ---- (R3-exact)
#define OFF_XHI      0ull            // bf16 [16384][768]
#define OFF_XLO      25165824ull     // bf16 [16384][768]
#define OFF_LCLS     0ull            // aliases XHI: bf16 [16384][768] class logits (cols 0..743 real)
#define OFF_LWE_P0   25165824ull     // f32 [16384][128] we partial, K-half 0 (+bias)  (aliases XLO)
#define OFF_LWE_P1   33554432ull     // f32 [16384][128] we partial, K-half 1
#define OFF_BT1      50331648ull     // bf16 [1536][768]  (cls_w1^T ; ew_w1^T)  [dead after gemm1]
#define OFF_LEWB     50331648ull     // bf16 [16384][128] ew logits (aliases BT1 region, written in gemm2)
#define OFF_BTWE_HI  52690944ull     // bf16 [768][768]
#define OFF_BTWE_LO  53870592ull
#define OFF_BT2CLS   55050240ull     // bf16 [768][768] (744 real rows, padded w/ 0)
#define OFF_BT2EW    56229888ull     // bf16 [128][768]
#define OFF_BT2WE_HI 56426496ull
#define OFF_BT2WE_LO 56623104ull
#define OFF_B1CE     56819712ull     // f32 [1536]
#define OFF_B1WE     56825856ull     // f32 [768]
#define OFF_B2CLS    56828928ull     // f32 [768]
#define OFF_B2EW     56832000ull     // f32 [128]
#define OFF_B2WE     56832512ull     // f32 [128]
#define OFF_HCLSEW   56833024ull     // bf16 [16384][1536] gelu(h) for cls|ew
#define OFF_HWE_HI   107164672ull    // bf16 [16384][768]
#define OFF_HWE_LO   132330496ull    // bf16 [16384][768]
#define WS_NEED      157496320ull

__device__ __forceinline__ u16 f2bf(float f) {          // RNE f32->bf16
  uint32_t u = __float_as_uint(f);
  u += 0x7fffu + ((u >> 16) & 1u);
  return (u16)(u >> 16);
}
__device__ __forceinline__ float bf2f(u16 h) {
  return __uint_as_float(((uint32_t)h) << 16);
}
__device__ __forceinline__ uint32_t pk2(float a, float b) {   // pack 2 bf16 into u32
  return (uint32_t)f2bf(a) | ((uint32_t)f2bf(b) << 16);
}
__device__ __forceinline__ void g2l16(const u16* g, u16* l) {
  // async global->LDS, 16B/lane; LDS dest = wave-uniform base + lane*16 (HW rule).
  // Global side is a normal per-lane address -> per-lane source permutation is legal.
  __builtin_amdgcn_global_load_lds(
      (__attribute__((address_space(1))) void*)(u16*)g,
      (__attribute__((address_space(3))) void*)l, 16, 0, 0);
}

// branch-free exact-GELU: 0.5*v*(1+erf(v/sqrt2)), erf via A&S 7.1.26 (|eps|<=1.5e-7).
__device__ __forceinline__ float gelu_exact(float v) {
  const float x = fabsf(v) * 0.70710678118654752f;
  const float t = __fdividef(1.0f, __builtin_fmaf(0.3275911f, x, 1.0f));
  float p = __builtin_fmaf(1.061405429f, t, -1.453152027f);
  p = __builtin_fmaf(p, t, 1.421413741f);
  p = __builtin_fmaf(p, t, -0.284496736f);
  p = __builtin_fmaf(p, t, 0.254829592f);
  p = p * t;
  const float e = __expf(-x * x);
  float erfx = __builtin_fmaf(-p, e, 1.0f);
  erfx = (v < 0.f) ? -erfx : erfx;
  return 0.5f * v * (1.0f + erfx);
}

// ---------------- merged prep: cvt_x split + weight transposes + bias concat ----------------
// grid layout: [0,12288) cvt_x ; [12288,13152) transpose (12x12x6) ; [13152,13165) bias
__global__ void prep_all(
    const float* __restrict__ x, u16* __restrict__ xhi, u16* __restrict__ xlo,
    const float* __restrict__ cls_w1, const float* __restrict__ ew_w1,
    const float* __restrict__ we_w1,  const float* __restrict__ cls_w2,
    const float* __restrict__ ew_w2,  const float* __restrict__ we_w2,
    u16* BT1, u16* BTwe_hi, u16* BTwe_lo,
    u16* BT2cls, u16* BT2ew, u16* BT2we_hi, u16* BT2we_lo,
    const float* __restrict__ cls_b1, const float* __restrict__ ew_b1,
    const float* __restrict__ we_b1,  const float* __restrict__ cls_b2,
    const float* __restrict__ ew_b2,  const float* __restrict__ we_b2,
    float* b1ce, float* b1we, float* b2cls, float* b2ew, float* b2we) {
  __shared__ float t[64][65];
  const int bid = blockIdx.x;
  if (bid < 12288) {                       // ---- x -> (hi,lo) bf16 split
    int i = bid * 256 + threadIdx.x;       // 12288*256 = 16384*768/4 exact
    float4 v = ((const float4*)x)[i];
    ushort4 h, l;
    h.x = f2bf(v.x); l.x = f2bf(v.x - bf2f(h.x));
    h.y = f2bf(v.y); l.y = f2bf(v.y - bf2f(h.y));
    h.z = f2bf(v.z); l.z = f2bf(v.z - bf2f(h.z));
    h.w = f2bf(v.w); l.w = f2bf(v.w - bf2f(h.w));
    ((ushort4*)xhi)[i] = h;
    ((ushort4*)xlo)[i] = l;
    return;
  }
  if (bid < 13152) {                       // ---- LDS-tiled transpose W[768][N] -> BT[Npad][768]
    const int idx = bid - 12288;
    const int bx = idx % 12, by = (idx / 12) % 12, bz = idx / 144;
    const float* src; int N; u16* dhi; u16* dlo = nullptr;
    switch (bz) {
      case 0: src = cls_w1; N = 768; dhi = BT1; break;
      case 1: src = ew_w1;  N = 768; dhi = BT1 + 768 * 768; break;
      case 2: src = we_w1;  N = 768; dhi = BTwe_hi; dlo = BTwe_lo; break;
      case 3: src = cls_w2; N = 744; dhi = BT2cls; break;
      case 4: src = ew_w2;  N = 124; dhi = BT2ew; break;
      default: src = we_w2; N = 124; dhi = BT2we_hi; dlo = BT2we_lo; break;
    }
    const int Npad = (N + 127) & ~127;
    const int n0 = by * 64;
    if (n0 >= Npad) return;
    const int k0 = bx * 64;
    const int tx = threadIdx.x & 63, tg = threadIdx.x >> 6;
#pragma unroll
    for (int r = 0; r < 16; ++r) {
      int k = tg * 16 + r;
      int n = n0 + tx;
      t[k][tx] = (n < N) ? src[(size_t)(k0 + k) * N + n] : 0.f;   // coalesced read
    }
    __syncthreads();
#pragma unroll
    for (int r = 0; r < 16; ++r) {
      int n = n0 + tg * 16 + r;
      if (n < Npad) {
        float v = t[tx][tg * 16 + r];
        u16 h = f2bf(v);
        dhi[(size_t)n * 768 + k0 + tx] = h;                       // coalesced write
        if (dlo) dlo[(size_t)n * 768 + k0 + tx] = f2bf(v - bf2f(h));
      }
    }
    return;
  }
  // ---- bias concat/pad: 13 blocks * 256 = 3328 = 1536+768+768+128+128 exact
  int id = (bid - 13152) * 256 + threadIdx.x;
  if (id < 1536) { b1ce[id] = (id < 768) ? cls_b1[id] : ew_b1[id - 768]; return; }
  id -= 1536;
  if (id < 768) { b1we[id] = we_b1[id]; return; }
  id -= 768;
  if (id < 768) { b2cls[id] = (id < 744) ? cls_b2[id] : 0.f; return; }
  id -= 768;
  if (id < 128) { b2ew[id] = (id < 124) ? ew_b2[id] : 0.f; return; }
  id -= 128;
  if (id < 128) { b2we[id] = (id < 124) ? we_b2[id] : 0.f; return; }
}

// ---------------- GEMM core: 128x128 tile, BK=64, 4 waves 2x2, XOR-swizzled LDS ----------------
// LDS: logical (row, c8) at physical c8p = c8 ^ (row&7) -> conflict-free ds_read_b128 (0 conflicts).
// MFMA operands SWAPPED (bv, av) -> acc holds C^T fragments: lane owns ONE row (lane&15 within
// frag) and 4 CONSECUTIVE cols ((lane>>4)*4 + r). Enables packed stores / LDS-bounce epilogue.
__device__ __forceinline__ void gemm_core(
    const u16* A0, int lda,
    const u16* B0,                                  // pre-offset by bn*K
    int K, int bm, int tid, u16* sA, u16* sB, f32x4 acc[4][4]) {
  const int lane = tid & 63;
  const int wv = tid >> 6;
  const int wr = wv >> 1, wc = wv & 1;
  const int sr = lane >> 3;                        // staging row within 8-row group
  const int sc = (((lane & 7) ^ sr) << 3);         // swizzled source col group
  const u16* gA = A0 + (size_t)(bm + wv * 32 + sr) * lda + sc;
  const u16* gB = B0 + (size_t)(wv * 32 + sr) * K + sc;
  u16* lA = sA + (wv * 32) * 64;
  u16* lB = sB + (wv * 32) * 64;
  for (int kt = 0; kt < K; kt += 64) {
#pragma unroll
    for (int s = 0; s < 4; ++s) {
      g2l16(gA + (size_t)(s * 8) * lda + kt, lA + s * 8 * 64);
      g2l16(gB + (size_t)(s * 8) * K + kt, lB + s * 8 * 64);
    }
    __syncthreads();
#pragma unroll
    for (int ks = 0; ks < 2; ++ks) {
      const int co = ((ks * 4 + (lane >> 4)) ^ (lane & 7)) * 8;  // row&7 == lane&7 for all frags
      short8 av[4], bv[4];
#pragma unroll
      for (int i = 0; i < 4; i++)
        av[i] = *(const short8*)(sA + (wr * 64 + i * 16 + (lane & 15)) * 64 + co);
#pragma unroll
      for (int j = 0; j < 4; j++)
        bv[j] = *(const short8*)(sB + (wc * 64 + j * 16 + (lane & 15)) * 64 + co);
#pragma unroll
      for (int i = 0; i < 4; i++)
#pragma unroll
        for (int j = 0; j < 4; j++)
          acc[i][j] = __builtin_amdgcn_mfma_f32_16x16x32_bf16(bv[j], av[i], acc[i][j], 0, 0, 0);
    }
    __syncthreads();
  }
}

// ---------------- packed hi/lo split core: C = Ahi*Bhi^T + Alo*Bhi^T + Ahi*Blo^T, ONE K-loop ----------------
// LDS rows pack [hi(32)|lo(32)] = 128B/row -> proven XOR-8 granule swizzle unchanged; hi/lo select
// is per-lane on the global_load_lds source address. 48 MFMA per wave per barrier-pair.
// MFMA operands swapped (C^T fragments) like gemm_core.
__device__ __forceinline__ void gemm_split_core(
    const u16* __restrict__ Ahi, const u16* __restrict__ Alo, int lda,
    const u16* __restrict__ Bhi, const u16* __restrict__ Blo, int ldb,  // pre-offset to tile row 0
    int K, int bm, int tid, u16* sA, u16* sB, f32x4 acc[4][4]) {
  const int lane = tid & 63;
  const int wv = tid >> 6;
  const int wr = wv >> 1, wc = wv & 1;
  const int sr = lane >> 3;                  // row within 8-row staging group
  const int gl = (lane & 7) ^ sr;            // logical granule at this lane's phys slot
  const int koff = (gl & 3) << 3;            // element offset within the 32-elem half
  const u16* Asel = (gl < 4) ? Ahi : Alo;
  const u16* Bsel = (gl < 4) ? Bhi : Blo;
  const u16* gA = Asel + (size_t)(bm + wv * 32 + sr) * lda + koff;
  const u16* gB = Bsel + (size_t)(wv * 32 + sr) * ldb + koff;
  u16* lA = sA + (wv * 32) * 64;
  u16* lB = sB + (wv * 32) * 64;

  for (int kt = 0; kt < K; kt += 32) {
#pragma unroll
    for (int s = 0; s < 4; ++s) {
      g2l16(gA + (size_t)(s * 8) * lda + kt, lA + s * 8 * 64);
      g2l16(gB + (size_t)(s * 8) * ldb + kt, lB + s * 8 * 64);
    }
    __syncthreads();
    // fragment granule: hi at (kg ^ row&7), lo at same ^ 4 -> element offset ^32
    const int coh = (((lane >> 4) ^ (lane & 7)) << 3);
    short8 ah[4], al[4], bh[4], bl[4];
#pragma unroll
    for (int i = 0; i < 4; i++) {
      const u16* p = sA + (wr * 64 + i * 16 + (lane & 15)) * 64;
      ah[i] = *(const short8*)(p + coh);
      al[i] = *(const short8*)(p + (coh ^ 32));
    }
#pragma unroll
    for (int j = 0; j < 4; j++) {
      const u16* p = sB + (wc * 64 + j * 16 + (lane & 15)) * 64;
      bh[j] = *(const short8*)(p + coh);
      bl[j] = *(const short8*)(p + (coh ^ 32));
    }
#pragma unroll
    for (int i = 0; i < 4; i++)
#pragma unroll
      for (int j = 0; j < 4; j++) {
        acc[i][j] = __builtin_amdgcn_mfma_f32_16x16x32_bf16(bh[j], ah[i], acc[i][j], 0, 0, 0);
        acc[i][j] = __builtin_amdgcn_mfma_f32_16x16x32_bf16(bh[j], al[i], acc[i][j], 0, 0, 0);
        acc[i][j] = __builtin_amdgcn_mfma_f32_16x16x32_bf16(bl[j], ah[i], acc[i][j], 0, 0, 0);
      }
    __syncthreads();
  }
}

// ---------------- LDS-bounce epilogue flush ----------------
// Tile staged in LDS as [128 rows][256 B], 8B granules XOR-swizzled: byte = row*256 + (cb ^ ((row&7)<<4)).
// Phase 2 here: each wave emits 4 FULL 256B rows per store instr -> every 64B line written once (no RMW).
__device__ __forceinline__ void bounce_flush(u16* dst, int ld, int tid, const u16* smem) {
  __syncthreads();                       // phase-1 LDS writes done
#pragma unroll
  for (int s = 0; s < 8; s++) {
    const int row = (s << 4) + (tid >> 4);
    const int M = tid & 15;
    const uint4 v = *(const uint4*)((const char*)(smem + row * 128) + ((M ^ (row & 7)) << 4));
    *(uint4*)(dst + (size_t)row * ld + (M << 3)) = v;
  }
}

// XCD/L2 swizzle for 128-row tiles: xcd=bid&7 owns 16 row-chunks; 8-row sub-bands, rows fastest.
__device__ __forceinline__ void decode_bid(int bid, int NC, int& bm, int& bn) {
  const int xcd = bid & 7, slot = bid >> 3;
  const int per = NC << 3;
  const int sub = slot / per, rem = slot - sub * per;
  const int colu = rem >> 3, rowIn = rem & 7;
  bm = ((xcd << 4) + (sub << 3) + rowIn) << 7;
  bn = colu << 7;
}

// ---------------- fused fc1: BOTH heads in one dispatch ----------------
// bid [0,768)    -> which_expert packed-split GEMM (heavy ~3x -> first)
// bid [768,2304) -> cls+ew GEMM (light, backfills residency gaps + tail)
__global__ __launch_bounds__(256, 4) void gemm1_fused(
    const u16* __restrict__ Ahi, const u16* __restrict__ Alo,      // xhi, xlo [16384][768]
    const u16* __restrict__ Bwe_hi, const u16* __restrict__ Bwe_lo,// we_w1^T splits [768][768]
    const u16* __restrict__ BT1,                                   // [cls_w1^T; ew_w1^T] [1536][768]
    const float* __restrict__ b1we, const float* __restrict__ b1ce,
    u16* __restrict__ out_we_hi, u16* __restrict__ out_we_lo,      // [16384][768]
    u16* __restrict__ out_ce) {                                    // [16384][1536]
  __shared__ u16 smem[2 * 128 * 64];
  u16* sA = smem;
  u16* sB = smem + 128 * 64;
  const int tid = threadIdx.x;
  const int lane = tid & 63;
  const int wr = (tid >> 6) >> 1, wc = (tid >> 6) & 1;
  const int lg4 = (lane >> 4) << 2;
  const int K = 768;

  f32x4 acc[4][4];
#pragma unroll
  for (int i = 0; i < 4; i++)
#pragma unroll
    for (int j = 0; j < 4; j++) acc[i][j] = f32x4{0.f, 0.f, 0.f, 0.f};

  if (blockIdx.x < 768) {
    // ===== which_expert fc1: packed-split, gelu -> bf16 hi + lo, LDS-bounce stores =====
    int bm, bn;
    decode_bid(blockIdx.x, 6, bm, bn);
    gemm_split_core(Ahi, Alo, K, Bwe_hi + (size_t)bn * K, Bwe_lo + (size_t)bn * K, K,
                    K, bm, tid, sA, sB, acc);
    // pass 1: hi tile -> LDS -> out_we_hi (acc stays live; gelu recomputed for lo pass)
#pragma unroll
    for (int i = 0; i < 4; i++) {
      const int row = wr * 64 + i * 16 + (lane & 15);
      char* lrow = (char*)(smem + row * 128);
      const int rsw = (row & 7) << 4;
#pragma unroll
      for (int j = 0; j < 4; j++) {
        const int col = wc * 64 + j * 16 + lg4;
        const float4 bs = *(const float4*)(b1we + bn + col);
        uint2 hv;
        hv.x = pk2(gelu_exact(acc[i][j][0] + bs.x), gelu_exact(acc[i][j][1] + bs.y));
        hv.y = pk2(gelu_exact(acc[i][j][2] + bs.z), gelu_exact(acc[i][j][3] + bs.w));
        *(uint2*)(lrow + ((col * 2) ^ rsw)) = hv;
      }
    }
    bounce_flush(out_we_hi + (size_t)bm * 768 + bn, 768, tid, smem);
    __syncthreads();                 // phase-2 reads done before overwrite
    // pass 2: lo tile (g recomputed bit-identically from live acc)
#pragma unroll
    for (int i = 0; i < 4; i++) {
      const int row = wr * 64 + i * 16 + (lane & 15);
      char* lrow = (char*)(smem + row * 128);
      const int rsw = (row & 7) << 4;
#pragma unroll
      for (int j = 0; j < 4; j++) {
        const int col = wc * 64 + j * 16 + lg4;
        const float4 bs = *(const float4*)(b1we + bn + col);
        float g0 = gelu_exact(acc[i][j][0] + bs.x);
        float g1 = gelu_exact(acc[i][j][1] + bs.y);
        float g2 = gelu_exact(acc[i][j][2] + bs.z);
        float g3 = gelu_exact(acc[i][j][3] + bs.w);
        uint2 lv;
        lv.x = pk2(g0 - bf2f(f2bf(g0)), g1 - bf2f(f2bf(g1)));
        lv.y = pk2(g2 - bf2f(f2bf(g2)), g3 - bf2f(f2bf(g3)));
        *(uint2*)(lrow + ((col * 2) ^ rsw)) = lv;
      }
    }
    bounce_flush(out_we_lo + (size_t)bm * 768 + bn, 768, tid, smem);
  } else {
    // ===== cls+ew fc1 (N=1536), gelu -> bf16, LDS-bounce stores =====
    int bm, bn;
    decode_bid(blockIdx.x - 768, 12, bm, bn);
    gemm_core(Ahi, 768, BT1 + (size_t)bn * K, K, bm, tid, sA, sB, acc);
#pragma unroll
    for (int i = 0; i < 4; i++) {
      const int row = wr * 64 + i * 16 + (lane & 15);
      char* lrow = (char*)(smem + row * 128);
      const int rsw = (row & 7) << 4;
#pragma unroll
      for (int j = 0; j < 4; j++) {
        const int col = wc * 64 + j * 16 + lg4;
        const float4 bs = *(const float4*)(b1ce + bn + col);
        uint2 hv;
        hv.x = pk2(gelu_exact(acc[i][j][0] + bs.x), gelu_exact(acc[i][j][1] + bs.y));
        hv.y = pk2(gelu_exact(acc[i][j][2] + bs.z), gelu_exact(acc[i][j][3] + bs.w));
        *(uint2*)(lrow + ((col * 2) ^ rsw)) = hv;
      }
    }
    bounce_flush(out_ce + (size_t)bm * 1536 + bn, 1536, tid, smem);
  }
}

// fused fc2 block plan (R3-exact):
//   bid [0,256)     -> we packed-split half-K blocks (heavy 1.5u -> first):
//                      half = bid>>7, row-chunk r = bid&127; K-range [half*384, half*384+384)
//                      acc = hi*Whi + lo*Whi + hi*Wlo over that K-half -> f32 partial p{half}
//   bid [256,1024)  -> cls (1u, 12 K-tiles)
//   bid [1024,1152) -> ew  (1u) -> bf16 Lew   (last: backfills the drain)
__global__ __launch_bounds__(256, 4) void gemm2_fused(
    const u16* __restrict__ h_cls,                  // [16384][1536]: cls cols 0..767, ew cols 768..1535
    const u16* __restrict__ hwe_hi, const u16* __restrict__ hwe_lo,
    const u16* __restrict__ BT2cls, const u16* __restrict__ BT2ew,
    const u16* __restrict__ BT2we_hi, const u16* __restrict__ BT2we_lo,
    const float* __restrict__ b2cls, const float* __restrict__ b2ew,
    const float* __restrict__ b2we,
    u16* __restrict__ Lcls, u16* __restrict__ LewB,
    float* __restrict__ p0, float* __restrict__ p1) {
  __shared__ u16 smem[2 * 128 * 64];
  u16* sA = smem;
  u16* sB = smem + 128 * 64;
  const int tid = threadIdx.x;
  const int lane = tid & 63;
  const int wr = (tid >> 6) >> 1, wc = (tid >> 6) & 1;
  const int lg4 = (lane >> 4) << 2;

  f32x4 acc[4][4];
#pragma unroll
  for (int i = 0; i < 4; i++)
#pragma unroll
    for (int j = 0; j < 4; j++) acc[i][j] = f32x4{0.f, 0.f, 0.f, 0.f};

  const int bid = blockIdx.x;
  if (bid < 256) {                         // ---- we fc2: packed-split, half-K, dwordx4 f32 stores
    const int half = bid >> 7;             //      (f32 quads already cover full 64B lines)
    const int r = bid & 127;
    const int bm = (((r & 7) << 4) + (r >> 3)) << 7;
    const int k0 = half * 384;
    gemm_split_core(hwe_hi + k0, hwe_lo + k0, 768,
                    BT2we_hi + k0, BT2we_lo + k0, 768,
                    384, bm, tid, sA, sB, acc);
    float* o = half ? p1 : p0;
#pragma unroll
    for (int i = 0; i < 4; i++) {
      const int row = bm + wr * 64 + i * 16 + (lane & 15);
#pragma unroll
      for (int j = 0; j < 4; j++) {
        const int colb = wc * 64 + j * 16 + lg4;
        float4 v;
        if (half) {
          v = make_float4(acc[i][j][0], acc[i][j][1], acc[i][j][2], acc[i][j][3]);
        } else {
          const float4 bs = *(const float4*)(b2we + colb);   // bias counted once (half 0)
          v = make_float4(acc[i][j][0] + bs.x, acc[i][j][1] + bs.y,
                          acc[i][j][2] + bs.z, acc[i][j][3] + bs.w);
        }
        *(float4*)(o + (size_t)row * 128 + colb) = v;
      }
    }
  } else if (bid < 1024) {                 // ---- cls: 6 col-tiles, LDS-bounce stores
    int bm, bn;
    decode_bid(bid - 256, 6, bm, bn);
    gemm_core(h_cls, 1536, BT2cls + (size_t)bn * 768, 768, bm, tid, sA, sB, acc);
#pragma unroll
    for (int i = 0; i < 4; i++) {
      const int row = wr * 64 + i * 16 + (lane & 15);
      char* lrow = (char*)(smem + row * 128);
      const int rsw = (row & 7) << 4;
#pragma unroll
      for (int j = 0; j < 4; j++) {
        const int col = wc * 64 + j * 16 + lg4;
        const float4 bs = *(const float4*)(b2cls + bn + col);
        uint2 hv;
        hv.x = pk2(acc[i][j][0] + bs.x, acc[i][j][1] + bs.y);
        hv.y = pk2(acc[i][j][2] + bs.z, acc[i][j][3] + bs.w);
        *(uint2*)(lrow + ((col * 2) ^ rsw)) = hv;
      }
    }
    bounce_flush(Lcls + (size_t)bm * 768 + bn, 768, tid, smem);
  } else {                                 // ---- ew (K=768 from h cols 768..1535) -> bf16, bounce
    const int r = bid - 1024;
    const int bm = (((r & 7) << 4) + (r >> 3)) << 7;
    gemm_core(h_cls + 768, 1536, BT2ew, 768, bm, tid, sA, sB, acc);
#pragma unroll
    for (int i = 0; i < 4; i++) {
      const int row = wr * 64 + i * 16 + (lane & 15);
      char* lrow = (char*)(smem + row * 128);
      const int rsw = (row & 7) << 4;
#pragma unroll
      for (int j = 0; j < 4; j++) {
        const int col = wc * 64 + j * 16 + lg4;
        const float4 bs = *(const float4*)(b2ew + col);
        uint2 hv;
        hv.x = pk2(acc[i][j][0] + bs.x, acc[i][j][1] + bs.y);
        hv.y = pk2(acc[i][j][2] + bs.z, acc[i][j][3] + bs.w);
        *(uint2*)(lrow + ((col * 2) ^ rsw)) = hv;
      }
    }
    bounce_flush(LewB + (size_t)bm * 128, 128, tid, smem);
  }
}

// ---------------- finalize: rank-select mask (== reference threshold), softmaxes, mixture ----------------
// which_expert = p0 + p1 (deterministic f32 sum of the two K-half partials).
// keep_i  <=>  which_i >= n-th largest  <=>  #{j : w_j > w_i} < n   (ties keep both, same as ref)
__global__ __launch_bounds__(256) void finalize(
    const u16* __restrict__ Lcls,   // bf16 [B][768], expert e at cols e*6..e*6+5
    const float* __restrict__ p0, const float* __restrict__ p1,
    const u16* __restrict__ LewB,   // bf16 [B][128]
    const int* __restrict__ nexp, float* __restrict__ out) {
  const int bid = blockIdx.x;
  const int g = ((bid & 7) << 9) + (bid >> 3);      // XCD band matches gemm2's row mapping
  const int b = (g << 2) + (int)(threadIdx.x >> 6); // 4 rows/block, one wave each
  const int lane = threadIdx.x & 63;
  const float NEG = -3.0e38f;
  const size_t base = (size_t)b * 128;
  const float w0 = (lane < 124) ? (p0[base + lane] + p1[base + lane]) : NEG;
  const float w1 = (lane < 60) ? (p0[base + 64 + lane] + p1[base + 64 + lane]) : NEG;
  int r0 = 0, r1 = 0;
#pragma unroll
  for (int j = 0; j < 64; ++j) {
    float v = __shfl(w0, j, 64);
    r0 += (v > w0); r1 += (v > w1);
  }
#pragma unroll
  for (int j = 0; j < 64; ++j) {
    float v = __shfl(w1, j, 64);
    r0 += (v > w0); r1 += (v > w1);
  }
  int n = nexp[b];
  n = n < 1 ? 1 : (n > 124 ? 124 : n);
  const bool k0 = (lane < 124) && (r0 < n);
  const bool k1 = (lane < 60) && (r1 < n);
  float l0 = k0 ? bf2f(LewB[base + lane]) : NEG;
  float l1 = k1 ? bf2f(LewB[base + 64 + lane]) : NEG;
  float mx = fmaxf(l0, l1);
#pragma unroll
  for (int o = 32; o > 0; o >>= 1) mx = fmaxf(mx, __shfl_xor(mx, o, 64));
  float e0 = k0 ? __expf(l0 - mx) : 0.f;
  float e1 = k1 ? __expf(l1 - mx) : 0.f;
  float S = e0 + e1;
#pragma unroll
  for (int o = 32; o > 0; o >>= 1) S += __shfl_xor(S, o, 64);
  float a0 = 0, a1 = 0, a2 = 0, a3 = 0, a4 = 0, a5 = 0;
#pragma unroll
  for (int h = 0; h < 2; ++h) {
    int e = lane + h * 64;
    float we = h ? e1 : e0;
    if (we > 0.f) {
      const u16* lp = Lcls + (size_t)b * 768 + e * 6;
      float c0 = bf2f(lp[0]), c1 = bf2f(lp[1]), c2 = bf2f(lp[2]);
      float c3 = bf2f(lp[3]), c4 = bf2f(lp[4]), c5 = bf2f(lp[5]);
      float m = fmaxf(fmaxf(fmaxf(c0, c1), fmaxf(c2, c3)), fmaxf(c4, c5));
      float q0 = __expf(c0 - m), q1 = __expf(c1 - m), q2 = __expf(c2 - m);
      float q3 = __expf(c3 - m), q4 = __expf(c4 - m), q5 = __expf(c5 - m);
      float inv = we / (q0 + q1 + q2 + q3 + q4 + q5);
      a0 += q0 * inv; a1 += q1 * inv; a2 += q2 * inv;
      a3 += q3 * inv; a4 += q4 * inv; a5 += q5 * inv;
    }
  }
#pragma unroll
  for (int o = 32; o > 0; o >>= 1) {
    a0 += __shfl_xor(a0, o, 64); a1 += __shfl_xor(a1, o, 64);
    a2 += __shfl_xor(a2, o, 64); a3 += __shfl_xor(a3, o, 64);
    a4 += __shfl_xor(a4, o, 64); a5 += __shfl_xor(a5, o, 64);
  }
  if (lane < 6) {
    float v = (lane == 0) ? a0 : (lane == 1) ? a1 : (lane == 2) ? a2
              : (lane == 3) ? a3 : (lane == 4) ? a4 : a5;
    out[(size_t)b * 6 + lane] = v / S;
  }
}

__global__ void fill_sentinel(float* out, int n, float v) {
  int i = blockIdx.x * 256 + threadIdx.x;
  if (i < n) out[i] = v;
}

extern "C" void kernel_launch(void* const* d_in, const int* in_sizes, int n_in,
                              void* d_out, int out_size, void* d_ws, size_t ws_size,
                              hipStream_t stream) {
  const float* x = (const float*)d_in[0];
  const int* nexp = (const int*)d_in[1];
  const float* cls_w1 = (const float*)d_in[2];
  const float* cls_b1 = (const float*)d_in[3];
  const float* cls_w2 = (const float*)d_in[4];
  const float* cls_b2 = (const float*)d_in[5];
  const float* we_w1 = (const float*)d_in[6];
  const float* we_b1 = (const float*)d_in[7];
  const float* we_w2 = (const float*)d_in[8];
  const float* we_b2 = (const float*)d_in[9];
  const float* ew_w1 = (const float*)d_in[10];
  const float* ew_b1 = (const float*)d_in[11];
  const float* ew_w2 = (const float*)d_in[12];
  const float* ew_b2 = (const float*)d_in[13];
  float* out = (float*)d_out;
  char* ws = (char*)d_ws;

  if (ws_size < WS_NEED) {  // diagnosable failure: absmax ~12345
    fill_sentinel<<<(out_size + 255) / 256, 256, 0, stream>>>(out, out_size, 12345.0f);
    return;
  }

  u16* xhi = (u16*)(ws + OFF_XHI);
  u16* xlo = (u16*)(ws + OFF_XLO);
  u16* Lcls = (u16*)(ws + OFF_LCLS);
  float* pwe0 = (float*)(ws + OFF_LWE_P0);
  float* pwe1 = (float*)(ws + OFF_LWE_P1);
  u16* LewB = (u16*)(ws + OFF_LEWB);
  u16* BT1 = (u16*)(ws + OFF_BT1);
  u16* BTwe_hi = (u16*)(ws + OFF_BTWE_HI);
  u16* BTwe_lo = (u16*)(ws + OFF_BTWE_LO);
  u16* BT2cls = (u16*)(ws + OFF_BT2CLS);
  u16* BT2ew = (u16*)(ws + OFF_BT2EW);
  u16* BT2we_hi = (u16*)(ws + OFF_BT2WE_HI);
  u16* BT2we_lo = (u16*)(ws + OFF_BT2WE_LO);
  float* b1ce = (float*)(ws + OFF_B1CE);
  float* b1we = (float*)(ws + OFF_B1WE);
  float* b2cls = (float*)(ws + OFF_B2CLS);
  float* b2ew = (float*)(ws + OFF_B2EW);
  float* b2we = (float*)(ws + OFF_B2WE);
  u16* h_clsew = (u16*)(ws + OFF_HCLSEW);
  u16* h_we_hi = (u16*)(ws + OFF_HWE_HI);
  u16* h_we_lo = (u16*)(ws + OFF_HWE_LO);

  prep_all<<<13165, 256, 0, stream>>>(x, xhi, xlo,
                                      cls_w1, ew_w1, we_w1, cls_w2, ew_w2, we_w2,
                                      BT1, BTwe_hi, BTwe_lo, BT2cls, BT2ew, BT2we_hi, BT2we_lo,
                                      cls_b1, ew_b1, we_b1, cls_b2, ew_b2, we_b2,
                                      b1ce, b1we, b2cls, b2ew, b2we);
  // fc1 BOTH heads in one dispatch: heavy packed-split we blocks first, cls/ew backfills
  gemm1_fused<<<2304, 256, 0, stream>>>(xhi, xlo, BTwe_hi, BTwe_lo, BT1,
                                        b1we, b1ce, h_we_hi, h_we_lo, h_clsew);
  // fc2: 1152 blocks; we packed-split half-K (1.5u) first, cls (1u), ew (1u) backfills drain
  gemm2_fused<<<1152, 256, 0, stream>>>(h_clsew, h_we_hi, h_we_lo,
                                        BT2cls, BT2ew, BT2we_hi, BT2we_lo,
                                        b2cls, b2ew, b2we,
                                        Lcls, LewB, pwe0, pwe1);
  finalize<<<4096, 256, 0, stream>>>(Lcls, pwe0, pwe1, LewB, nexp, out);
}